// Round 2
// baseline (635.484 us; speedup 1.0000x reference)
//
#include <hip/hip_runtime.h>

// Problem: VoxelMorph flow pipeline.
// features [16,128,128,128] f32, moving_label [1,128,128,128] f32,
// weight [3,16,3,3,3] f32, bias [3] f32.
// Output: moved [128^3] then flow [3*128^3], f32, concatenated flat.
//
// R6: single regular dispatch + SOFTWARE grid barrier.
// R5's hipLaunchCooperativeKernel produced garbage under the harness's graph
// capture (cooperative property lost -> grid.sync() no-op -> races). Replace
// with a generation-counter barrier using device-scope atomics + threadfence
// (graph-capture-safe: it is just memory traffic).
// Co-residency by capacity arithmetic: LDS 53,664B/block -> <=3 blocks/CU;
// launch_bounds(256,2) -> VGPR<=256 (build is 72) -> capacity >= 768 blocks
// > 512 launched, so all blocks are resident; barrier cannot deadlock.
// Phases (bodies identical to the verified 4-dispatch version):
//   A: conv 16->3 (1024 tiles, 2 per block)
//   B: downsample+scale + integration steps 1-3
//   C: integration steps 4-6
//   D: step 7 + upsample + label warp

#define V128 2097152      // 128^3
#define V64  262144       // 64^3
#define NBLK 512

// ---------------- software grid barrier ------------------------------------
// bar[0] = arrival count, bar[1] = generation. count must be 0 at launch
// (memset in kernel_launch); generation value is read fresh so any start
// value works, and the barrier leaves count==0 for the next use.
__device__ __forceinline__ void gbar(unsigned* bar) {
    __syncthreads();
    if (threadIdx.x == 0) {
        __threadfence();  // release: publish this block's writes (agent scope)
        unsigned g = __hip_atomic_load(bar + 1, __ATOMIC_RELAXED,
                                       __HIP_MEMORY_SCOPE_AGENT);
        unsigned prev = __hip_atomic_fetch_add(bar, 1u, __ATOMIC_ACQ_REL,
                                               __HIP_MEMORY_SCOPE_AGENT);
        if (prev == NBLK - 1) {
            __hip_atomic_store(bar, 0u, __ATOMIC_RELAXED,
                               __HIP_MEMORY_SCOPE_AGENT);
            __hip_atomic_fetch_add(bar + 1, 1u, __ATOMIC_ACQ_REL,
                                   __HIP_MEMORY_SCOPE_AGENT);
        } else {
            while (__hip_atomic_load(bar + 1, __ATOMIC_ACQUIRE,
                                     __HIP_MEMORY_SCOPE_AGENT) == g) {
                __builtin_amdgcn_s_sleep(8);
            }
        }
        __threadfence();  // acquire: make other blocks' writes visible
    }
    __syncthreads();
}

// ---------------- trilinear sampler (matches reference _sample) -------------
template <int C>
__device__ __forceinline__ void trisample(const float* __restrict__ vol,
                                          int D, int H, int W, int cstride,
                                          float cz, float cy, float cx,
                                          float* out) {
    float fz = floorf(cz), fy = floorf(cy), fx = floorf(cx);
    int iz = (int)fz, iy = (int)fy, ix = (int)fx;
    float tz = cz - fz, ty = cy - fy, tx = cx - fx;
#pragma unroll
    for (int c = 0; c < C; ++c) out[c] = 0.0f;
#pragma unroll
    for (int dz = 0; dz < 2; ++dz) {
#pragma unroll
        for (int dy = 0; dy < 2; ++dy) {
#pragma unroll
            for (int dx = 0; dx < 2; ++dx) {
                int z = iz + dz, y = iy + dy, x = ix + dx;
                float w = (dz ? tz : 1.0f - tz) *
                          (dy ? ty : 1.0f - ty) *
                          (dx ? tx : 1.0f - tx);
                bool valid = (z >= 0) && (z < D) && (y >= 0) && (y < H) &&
                             (x >= 0) && (x < W);
                int zc = min(max(z, 0), D - 1);
                int yc = min(max(y, 0), H - 1);
                int xc = min(max(x, 0), W - 1);
                int base = (zc * H + yc) * W + xc;
                float wv = valid ? w : 0.0f;
#pragma unroll
                for (int c = 0; c < C; ++c)
                    out[c] += vol[c * cstride + base] * wv;
            }
        }
    }
}

// -------- LDS trilerp, 3 channels, no bounds checks (caller guarantees) ----
template <int SI>
__device__ __forceinline__ void lds_lerp3(const float* __restrict__ f,
                                          float pz, float py, float px,
                                          float* out) {
    constexpr int NI = SI * SI * SI;
    float fz = floorf(pz), fy = floorf(py), fx = floorf(px);
    int iz = (int)fz, iy = (int)fy, ix = (int)fx;
    float tz = pz - fz, ty = py - fy, tx = px - fx;
    int b = (iz * SI + iy) * SI + ix;
    float wz0 = 1.0f - tz, wy0 = 1.0f - ty, wx0 = 1.0f - tx;
#pragma unroll
    for (int c = 0; c < 3; ++c) {
        const float* fc = f + c * NI;
        float v00 = fc[b] * wx0 + fc[b + 1] * tx;
        float v01 = fc[b + SI] * wx0 + fc[b + SI + 1] * tx;
        float v10 = fc[b + SI * SI] * wx0 + fc[b + SI * SI + 1] * tx;
        float v11 = fc[b + SI * SI + SI] * wx0 + fc[b + SI * SI + SI + 1] * tx;
        out[c] = wz0 * (wy0 * v00 + ty * v01) + tz * (wy0 * v10 + ty * v11);
    }
}

// -------- one integration step LDS->LDS: out region = in region shrunk by 1 -
template <int SI>
__device__ __forceinline__ void step_lds(const float* __restrict__ in,
                                         float* __restrict__ out, int tid) {
    constexpr int SO = SI - 2;
    constexpr int NI = SI * SI * SI;
    constexpr int NO = SO * SO * SO;
    for (int i = tid; i < NO; i += 256) {
        int xx = i % SO, yy = (i / SO) % SO, zz = i / (SO * SO);
        int la = ((zz + 1) * SI + (yy + 1)) * SI + (xx + 1);
        float fz = in[la], fy = in[la + NI], fx = in[la + 2 * NI];
        float sm[3];
        lds_lerp3<SI>(in, (zz + 1) + fz, (yy + 1) + fy, (xx + 1) + fx, sm);
        out[i] = fz + sm[0];
        out[i + NO] = fy + sm[1];
        out[i + 2 * NO] = fx + sm[2];
    }
}

// -------- last fused step: in region 10^3 (frame = tile-1) -> global 8^3 ----
__device__ __forceinline__ void step_to_global(const float* __restrict__ in,
                                               float* __restrict__ gout,
                                               int tx, int ty, int tz,
                                               int tid) {
    constexpr int SI = 10;
    constexpr int NI = SI * SI * SI;
    for (int i = tid; i < 512; i += 256) {
        int xx = i & 7, yy = (i >> 3) & 7, zz = i >> 6;
        int la = ((zz + 1) * SI + (yy + 1)) * SI + (xx + 1);
        float fz = in[la], fy = in[la + NI], fx = in[la + 2 * NI];
        float sm[3];
        lds_lerp3<SI>(in, (zz + 1) + fz, (yy + 1) + fy, (xx + 1) + fx, sm);
        int n = ((tz + zz) << 12) + ((ty + yy) << 6) + (tx + xx);
        gout[n] = fz + sm[0];
        gout[n + V64] = fy + sm[1];
        gout[n + 2 * V64] = fx + sm[2];
    }
}

// ---------------- phase A: conv3d 16->3, 3x3x3, pad 1 (body unchanged) ------
__device__ void conv_tile(const float* __restrict__ feat,
                          const float* __restrict__ weight,
                          const float* __restrict__ bias,
                          float* __restrict__ pos_flow,
                          float* __restrict__ sm, int x0, int y0, int z0) {
    float (*smem)[3960] = (float (*)[3960])sm;
    const int tid = threadIdx.x;
    const int lx = tid & 63, ly = tid >> 6;

    int goff[16];
    unsigned vmask = 0;
    {
        int xx = tid % 66;
        int r = tid / 66;
        int yy = r % 6;
        int zz = r / 6;
#pragma unroll
        for (int k = 0; k < 16; ++k) {
            bool intile = (k < 15) || (tid < 120);
            int gx = x0 + xx - 1, gy = y0 + yy - 1, gz = z0 + zz - 1;
            bool ok = intile && ((unsigned)gx < 128u) &&
                      ((unsigned)gy < 128u) && ((unsigned)gz < 128u);
            goff[k] = (gz << 14) + (gy << 7) + gx;
            if (ok) vmask |= (1u << k);
            xx += 58;
            yy += 3;
            if (xx >= 66) { xx -= 66; yy += 1; }
            if (yy >= 6) { yy -= 6; zz += 1; }
        }
    }

    typedef __attribute__((ext_vector_type(2))) float f32x2;
    f32x2 acc[3][4];
#pragma unroll
    for (int o = 0; o < 3; ++o)
#pragma unroll
        for (int zp = 0; zp < 4; ++zp) acc[o][zp] = (f32x2)(0.0f);

    {
        float vals[16];
#pragma unroll
        for (int k = 0; k < 16; ++k) {
            vals[k] = 0.0f;
            if (vmask & (1u << k)) vals[k] = feat[goff[k]];
        }
#pragma unroll
        for (int k = 0; k < 16; ++k)
            if (k < 15 || tid < 120) smem[0][tid + 256 * k] = vals[k];
    }

    for (int c = 0; c < 16; ++c) {
        __syncthreads();
        if (c + 1 < 16) {
            const float* fc = feat + ((c + 1) << 21);
            float* buf = smem[(c + 1) & 1];
            float vals[16];
#pragma unroll
            for (int k = 0; k < 16; ++k) {
                vals[k] = 0.0f;
                if (vmask & (1u << k)) vals[k] = fc[goff[k]];
            }
#pragma unroll
            for (int k = 0; k < 16; ++k)
                if (k < 15 || tid < 120) buf[tid + 256 * k] = vals[k];
        }
        const float* buf = smem[c & 1];
        const float* wc = weight + c * 27;
#pragma unroll
        for (int dy = 0; dy < 3; ++dy) {
#pragma unroll
            for (int dx = 0; dx < 3; ++dx) {
                const float* p = buf + (ly + dy) * 66 + lx + dx;
                float v[10];
#pragma unroll
                for (int zz = 0; zz < 10; ++zz) v[zz] = p[zz * 396];
#pragma unroll
                for (int dz = 0; dz < 3; ++dz) {
#pragma unroll
                    for (int o = 0; o < 3; ++o) {
                        float w = wc[o * 432 + dz * 9 + dy * 3 + dx];
#pragma unroll
                        for (int zp = 0; zp < 4; ++zp) {
                            acc[o][zp].x += v[2 * zp + dz] * w;
                            acc[o][zp].y += v[2 * zp + dz + 1] * w;
                        }
                    }
                }
            }
        }
    }

#pragma unroll
    for (int o = 0; o < 3; ++o) {
        float b = bias[o];
#pragma unroll
        for (int zp = 0; zp < 4; ++zp) {
            int z = z0 + 2 * zp;
            int base = o * V128 + ((y0 + ly) << 7) + x0 + lx;
            pos_flow[base + (z << 14)] = acc[o][zp].x + b;
            pos_flow[base + ((z + 1) << 14)] = acc[o][zp].y + b;
        }
    }
}

// ------- phase B: downsample on 14^3 halo region, then steps 1-3 -----------
__device__ void f2_body(const float* __restrict__ pos_flow,
                        float* __restrict__ gout, float* __restrict__ sm,
                        int tx, int ty, int tz) {
    float* A = sm;             // 3 * 2744 (14^3)
    float* B = sm + 3 * 2744;  // 3 * 1728 (12^3)
    const int tid = threadIdx.x;
    const int rbx = tx - 3, rby = ty - 3, rbz = tz - 3;
    const float s2 = 127.0f / 63.0f;
    const float k = 1.0f / 256.0f;
    for (int i = tid; i < 2744; i += 256) {
        int xx = i % 14, yy = (i / 14) % 14, zz = i / 196;
        int gz = rbz + zz, gy = rby + yy, gx = rbx + xx;
        float v[3] = {0.0f, 0.0f, 0.0f};
        if ((unsigned)gz < 64u && (unsigned)gy < 64u && (unsigned)gx < 64u)
            trisample<3>(pos_flow, 128, 128, 128, V128, gz * s2, gy * s2,
                         gx * s2, v);
        A[i] = v[0] * k;
        A[i + 2744] = v[1] * k;
        A[i + 2 * 2744] = v[2] * k;
    }
    __syncthreads();
    step_lds<14>(A, B, tid);
    __syncthreads();
    step_lds<12>(B, A, tid);
    __syncthreads();
    step_to_global(A, gout, tx, ty, tz, tid);
}

// ------- phase C: steps 4-6 (stage 14^3 from global, zero-extended) --------
__device__ void f3_body(const float* __restrict__ gin,
                        float* __restrict__ gout, float* __restrict__ sm,
                        int tx, int ty, int tz) {
    float* A = sm;
    float* B = sm + 3 * 2744;
    const int tid = threadIdx.x;
    const int rbx = tx - 3, rby = ty - 3, rbz = tz - 3;
    for (int i = tid; i < 2744; i += 256) {
        int xx = i % 14, yy = (i / 14) % 14, zz = i / 196;
        int gz = rbz + zz, gy = rby + yy, gx = rbx + xx;
        float v0 = 0.0f, v1 = 0.0f, v2 = 0.0f;
        if ((unsigned)gz < 64u && (unsigned)gy < 64u && (unsigned)gx < 64u) {
            int n = (gz << 12) + (gy << 6) + gx;
            v0 = gin[n];
            v1 = gin[n + V64];
            v2 = gin[n + 2 * V64];
        }
        A[i] = v0;
        A[i + 2744] = v1;
        A[i + 2 * 2744] = v2;
    }
    __syncthreads();
    step_lds<14>(A, B, tid);
    __syncthreads();
    step_lds<12>(B, A, tid);
    __syncthreads();
    step_to_global(A, gout, tx, ty, tz, tid);
}

// ------- phase D: step 7 + upsample(x2) -> flow + label warp -> moved ------
__device__ void f4_body(const float* __restrict__ gin,
                        const float* __restrict__ label,
                        float* __restrict__ moved, float* __restrict__ flow,
                        float* __restrict__ sm, int ttx, int tty, int ttz) {
    float* A = sm;             // 3 * 2197 (13^3)
    float* B = sm + 3 * 2197;  // 3 * 1331 (11^3)
    const int tid = threadIdx.x;
    const int r0x = (1008 * ttx) / 127 - 1;
    const int r0y = (1008 * tty) / 127 - 1;
    const int r0z = (1008 * ttz) / 127 - 1;
    const int rbx = r0x - 1, rby = r0y - 1, rbz = r0z - 1;
    for (int i = tid; i < 2197; i += 256) {
        int xx = i % 13, yy = (i / 13) % 13, zz = i / 169;
        int gz = rbz + zz, gy = rby + yy, gx = rbx + xx;
        float v0 = 0.0f, v1 = 0.0f, v2 = 0.0f;
        if ((unsigned)gz < 64u && (unsigned)gy < 64u && (unsigned)gx < 64u) {
            int n = (gz << 12) + (gy << 6) + gx;
            v0 = gin[n];
            v1 = gin[n + V64];
            v2 = gin[n + 2 * V64];
        }
        A[i] = v0;
        A[i + 2197] = v1;
        A[i + 2 * 2197] = v2;
    }
    __syncthreads();
    step_lds<13>(A, B, tid);  // s7: 11^3 in B, frame base = r0
    __syncthreads();
    const float s3 = 63.0f / 127.0f;
    for (int i = tid; i < 4096; i += 256) {
        int lx = i & 15, ly = (i >> 4) & 15, lz = i >> 8;
        int gx = ttx * 16 + lx, gy = tty * 16 + ly, gz = ttz * 16 + lz;
        float f[3];
        lds_lerp3<11>(B, gz * s3 - (float)r0z, gy * s3 - (float)r0y,
                      gx * s3 - (float)r0x, f);
        float fz = 2.0f * f[0], fy = 2.0f * f[1], fx = 2.0f * f[2];
        int m = (gz << 14) + (gy << 7) + gx;
        flow[m] = fz;
        flow[m + V128] = fy;
        flow[m + 2 * V128] = fx;
        float mv[1];
        trisample<1>(label, 128, 128, 128, 0, gz + fz, gy + fy, gx + fx, mv);
        moved[m] = mv[0];
    }
}

// ---------------- mega kernel: all 4 phases, 3 software grid barriers ------
__global__ __launch_bounds__(256, 2) void mega_kernel(
    const float* __restrict__ feat, const float* __restrict__ weight,
    const float* __restrict__ bias, const float* __restrict__ label,
    float* __restrict__ moved, float* __restrict__ flow,
    float* __restrict__ fA, float* __restrict__ fB, unsigned* bar) {
    __shared__ float sm[13416];  // 53,664 B -> <=3 blocks/CU; 512 resident
    const int bid = blockIdx.x;

    // Phase A: conv. 1024 tiles (2,32,16 decomposition), 2 per block.
    for (int job = bid; job < 1024; job += NBLK) {
        int x0 = (job & 1) * 64;
        int y0 = ((job >> 1) & 31) * 4;
        int z0 = (job >> 6) * 8;
        conv_tile(feat, weight, bias, flow, sm, x0, y0, z0);
        __syncthreads();  // smem reused by next job's staging
    }
    gbar(bar);

    // Phase B: downsample + steps 1-3 -> fA (g3)
    f2_body(flow, fA, sm, (bid & 7) * 8, ((bid >> 3) & 7) * 8,
            (bid >> 6) * 8);
    gbar(bar);

    // Phase C: steps 4-6 -> fB (g6)
    f3_body(fA, fB, sm, (bid & 7) * 8, ((bid >> 3) & 7) * 8, (bid >> 6) * 8);
    gbar(bar);

    // Phase D: step 7 + upsample + warp -> moved, flow
    f4_body(fB, label, moved, flow, sm, bid & 7, (bid >> 3) & 7, bid >> 6);
}

extern "C" void kernel_launch(void* const* d_in, const int* in_sizes, int n_in,
                              void* d_out, int out_size, void* d_ws,
                              size_t ws_size, hipStream_t stream) {
    const float* features = (const float*)d_in[0];
    const float* label = (const float*)d_in[1];
    const float* weight = (const float*)d_in[2];
    const float* bias = (const float*)d_in[3];
    float* out = (float*)d_out;
    float* moved = out;        // 128^3 floats
    float* flow = out + V128;  // 3*128^3 floats; also pos_flow scratch
    float* fA = (float*)d_ws;  // 3*64^3 floats (g3)
    float* fB = fA + 3 * V64;  // 3*64^3 floats (g6)
    // Barrier state at the aligned tail of the workspace (disjoint from
    // fA/fB as long as ws_size >= 6MB + 64B).
    size_t bar_off = (ws_size - 64) & ~(size_t)63;
    unsigned* bar = (unsigned*)((char*)d_ws + bar_off);

    hipMemsetAsync(bar, 0, 16, stream);  // count=0 (gen value irrelevant)
    mega_kernel<<<dim3(NBLK), dim3(256), 0, stream>>>(
        features, weight, bias, label, moved, flow, fA, fB, bar);
}

// Round 4
// 331.514 us; speedup vs baseline: 1.9169x; 1.9169x over previous
//
#include <hip/hip_runtime.h>

// Problem: VoxelMorph flow pipeline.
// features [16,128,128,128] f32, moving_label [1,128,128,128] f32,
// weight [3,16,3,3,3] f32, bias [3] f32.
// Output: moved [128^3] then flow [3*128^3], f32, concatenated flat.
//
// R8 = R7 + boundary fix. R7 crashed: at gz=63, cz=63*(127/63) rounds to
// exactly 127.0; the unguarded dz=1 corner then reads voxel z=128 -> OOB
// past the output buffer. Fix: clamp corner base to <=126 and recompute the
// fraction (iz=126,t=1.0 == reference's zero-weight masked corner, exact).
// Changes vs the 327.7us 4-dispatch baseline:
//  (1) conv: z-innermost LDS tile -> z-pair f32x2 accumulation
//      (v_pk_fma_f32), pair LDS loads (ds_read_b64 / ds_read2_b32).
//  (2) intermediates (pos_flow scratch, g3, g6) stored INTERLEAVED
//      [vox][3]: each trilinear corner is one 12B load instead of three
//      channel-strided 4B loads (phases are latency-bound, ~6.5% VALUBusy).

#define V128 2097152      // 128^3
#define V64  262144       // 64^3

typedef __attribute__((ext_vector_type(2))) float f32x2;
typedef float f32x2u __attribute__((ext_vector_type(2), aligned(4)));

// ---------------- trilinear sampler (bounds-checked; label warp) -----------
template <int C>
__device__ __forceinline__ void trisample(const float* __restrict__ vol,
                                          int D, int H, int W, int cstride,
                                          float cz, float cy, float cx,
                                          float* out) {
    float fz = floorf(cz), fy = floorf(cy), fx = floorf(cx);
    int iz = (int)fz, iy = (int)fy, ix = (int)fx;
    float tz = cz - fz, ty = cy - fy, tx = cx - fx;
#pragma unroll
    for (int c = 0; c < C; ++c) out[c] = 0.0f;
#pragma unroll
    for (int dz = 0; dz < 2; ++dz) {
#pragma unroll
        for (int dy = 0; dy < 2; ++dy) {
#pragma unroll
            for (int dx = 0; dx < 2; ++dx) {
                int z = iz + dz, y = iy + dy, x = ix + dx;
                float w = (dz ? tz : 1.0f - tz) *
                          (dy ? ty : 1.0f - ty) *
                          (dx ? tx : 1.0f - tx);
                bool valid = (z >= 0) && (z < D) && (y >= 0) && (y < H) &&
                             (x >= 0) && (x < W);
                int zc = min(max(z, 0), D - 1);
                int yc = min(max(y, 0), H - 1);
                int xc = min(max(x, 0), W - 1);
                int base = (zc * H + yc) * W + xc;
                float wv = valid ? w : 0.0f;
#pragma unroll
                for (int c = 0; c < C; ++c)
                    out[c] += vol[c * cstride + base] * wv;
            }
        }
    }
}

// -------- LDS trilerp, 3 channels, no bounds checks (caller guarantees) ----
template <int SI>
__device__ __forceinline__ void lds_lerp3(const float* __restrict__ f,
                                          float pz, float py, float px,
                                          float* out) {
    constexpr int NI = SI * SI * SI;
    float fz = floorf(pz), fy = floorf(py), fx = floorf(px);
    int iz = (int)fz, iy = (int)fy, ix = (int)fx;
    float tz = pz - fz, ty = py - fy, tx = px - fx;
    int b = (iz * SI + iy) * SI + ix;
    float wz0 = 1.0f - tz, wy0 = 1.0f - ty, wx0 = 1.0f - tx;
#pragma unroll
    for (int c = 0; c < 3; ++c) {
        const float* fc = f + c * NI;
        float v00 = fc[b] * wx0 + fc[b + 1] * tx;
        float v01 = fc[b + SI] * wx0 + fc[b + SI + 1] * tx;
        float v10 = fc[b + SI * SI] * wx0 + fc[b + SI * SI + 1] * tx;
        float v11 = fc[b + SI * SI + SI] * wx0 + fc[b + SI * SI + SI + 1] * tx;
        out[c] = wz0 * (wy0 * v00 + ty * v01) + tz * (wy0 * v10 + ty * v11);
    }
}

// -------- one integration step LDS->LDS: out region = in region shrunk by 1 -
template <int SI>
__device__ __forceinline__ void step_lds(const float* __restrict__ in,
                                         float* __restrict__ out, int tid) {
    constexpr int SO = SI - 2;
    constexpr int NI = SI * SI * SI;
    constexpr int NO = SO * SO * SO;
    for (int i = tid; i < NO; i += 256) {
        int xx = i % SO, yy = (i / SO) % SO, zz = i / (SO * SO);
        int la = ((zz + 1) * SI + (yy + 1)) * SI + (xx + 1);
        float fz = in[la], fy = in[la + NI], fx = in[la + 2 * NI];
        float sm[3];
        lds_lerp3<SI>(in, (zz + 1) + fz, (yy + 1) + fy, (xx + 1) + fx, sm);
        out[i] = fz + sm[0];
        out[i + NO] = fy + sm[1];
        out[i + 2 * NO] = fx + sm[2];
    }
}

// -------- last fused step: 10^3 region -> global 8^3, interleaved [vox][3] --
__device__ __forceinline__ void step_to_global(const float* __restrict__ in,
                                               float* __restrict__ gout,
                                               int tx, int ty, int tz,
                                               int tid) {
    constexpr int SI = 10;
    constexpr int NI = SI * SI * SI;
    for (int i = tid; i < 512; i += 256) {
        int xx = i & 7, yy = (i >> 3) & 7, zz = i >> 6;
        int la = ((zz + 1) * SI + (yy + 1)) * SI + (xx + 1);
        float fz = in[la], fy = in[la + NI], fx = in[la + 2 * NI];
        float sm[3];
        lds_lerp3<SI>(in, (zz + 1) + fz, (yy + 1) + fy, (xx + 1) + fx, sm);
        int n3 = ((((tz + zz) << 12) + ((ty + yy) << 6) + (tx + xx))) * 3;
        gout[n3] = fz + sm[0];
        gout[n3 + 1] = fy + sm[1];
        gout[n3 + 2] = fx + sm[2];
    }
}

// ---------------- K1: conv3d 16->3, 3x3x3, pad 1 ---------------------------
// Staged tile layout is z-INNERMOST: linear index s enumerates
// (zz = s%10, xx = (s/10)%66, yy = s/660). z-pairs are then adjacent in LDS:
// pv[k] = (v[2k], v[2k+1]) is an aligned ds_read_b64 (base mult. of 40B),
// qv[k] = (v[2k+1], v[2k+2]) is a 4B-aligned pair load. Accumulators are
// f32x2 z-pairs -> packed v_pk_fma_f32. Output interleaved [vox][3].
__global__ __launch_bounds__(256) void conv_kernel(
    const float* __restrict__ feat, const float* __restrict__ weight,
    const float* __restrict__ bias, float* __restrict__ pf) {
    __shared__ float smem[2][3960];
    const int tid = threadIdx.x;
    const int x0 = blockIdx.x * 64, y0 = blockIdx.y * 4, z0 = blockIdx.z * 8;
    const int lx = tid & 63, ly = tid >> 6;

    int goff[16];
    unsigned vmask = 0;
#pragma unroll
    for (int k = 0; k < 16; ++k) {
        int s = tid + 256 * k;
        int zz = s % 10;
        int r = s / 10;
        int xx = r % 66;
        int yy = r / 66;
        bool intile = (k < 15) || (tid < 120);
        int gx = x0 + xx - 1, gy = y0 + yy - 1, gz = z0 + zz - 1;
        bool ok = intile && ((unsigned)gx < 128u) && ((unsigned)gy < 128u) &&
                  ((unsigned)gz < 128u);
        goff[k] = (gz << 14) + (gy << 7) + gx;
        if (ok) vmask |= (1u << k);
    }

    f32x2 acc[3][4];
#pragma unroll
    for (int o = 0; o < 3; ++o)
#pragma unroll
        for (int zp = 0; zp < 4; ++zp) acc[o][zp] = (f32x2)(0.0f);

    {
        float vals[16];
#pragma unroll
        for (int k = 0; k < 16; ++k) {
            vals[k] = 0.0f;
            if (vmask & (1u << k)) vals[k] = feat[goff[k]];
        }
#pragma unroll
        for (int k = 0; k < 16; ++k)
            if (k < 15 || tid < 120) smem[0][tid + 256 * k] = vals[k];
    }

    for (int c = 0; c < 16; ++c) {
        __syncthreads();
        if (c + 1 < 16) {
            const float* fc = feat + ((c + 1) << 21);
            float* buf = smem[(c + 1) & 1];
            float vals[16];
#pragma unroll
            for (int k = 0; k < 16; ++k) {
                vals[k] = 0.0f;
                if (vmask & (1u << k)) vals[k] = fc[goff[k]];
            }
#pragma unroll
            for (int k = 0; k < 16; ++k)
                if (k < 15 || tid < 120) buf[tid + 256 * k] = vals[k];
        }
        const float* buf = smem[c & 1];
        const float* wc = weight + c * 27;
#pragma unroll
        for (int dy = 0; dy < 3; ++dy) {
#pragma unroll
            for (int dx = 0; dx < 3; ++dx) {
                const float* p = buf + ((ly + dy) * 66 + lx + dx) * 10;
                f32x2 pv[5];
                f32x2 qv[4];
#pragma unroll
                for (int k2 = 0; k2 < 5; ++k2)
                    pv[k2] = *(const f32x2*)(p + 2 * k2);
#pragma unroll
                for (int k2 = 0; k2 < 4; ++k2)
                    qv[k2] = *(const f32x2u*)(p + 2 * k2 + 1);
#pragma unroll
                for (int o = 0; o < 3; ++o) {
                    float w0 = wc[o * 432 + 0 + dy * 3 + dx];
                    float w1 = wc[o * 432 + 9 + dy * 3 + dx];
                    float w2 = wc[o * 432 + 18 + dy * 3 + dx];
#pragma unroll
                    for (int zp = 0; zp < 4; ++zp) {
                        acc[o][zp] += pv[zp] * (f32x2)(w0);
                        acc[o][zp] += qv[zp] * (f32x2)(w1);
                        acc[o][zp] += pv[zp + 1] * (f32x2)(w2);
                    }
                }
            }
        }
    }

    float b0 = bias[0], b1 = bias[1], b2 = bias[2];
#pragma unroll
    for (int zp = 0; zp < 4; ++zp) {
        int vox0 = ((z0 + 2 * zp) << 14) + ((y0 + ly) << 7) + x0 + lx;
#pragma unroll
        for (int h = 0; h < 2; ++h) {
            int m3 = (vox0 + (h << 14)) * 3;
            pf[m3] = (h ? acc[0][zp].y : acc[0][zp].x) + b0;
            pf[m3 + 1] = (h ? acc[1][zp].y : acc[1][zp].x) + b1;
            pf[m3 + 2] = (h ? acc[2][zp].y : acc[2][zp].x) + b2;
        }
    }
}

// ------- F2: downsample(x1/256) on 14^3 halo region, then steps 1-3 --------
// pf is interleaved [vox][3]; each corner is one 12B load.
// Corner base clamped to <=126 per dim (at coord exactly 127.0 this gives
// i=126,t=1.0 == reference's zero-weight masked upper corner, exact).
__global__ __launch_bounds__(256) void f2_kernel(
    const float* __restrict__ pf, float* __restrict__ gout) {
    __shared__ float A[3 * 2744];  // 14^3
    __shared__ float B[3 * 1728];  // 12^3
    const int tid = threadIdx.x;
    const int tx = blockIdx.x * 8, ty = blockIdx.y * 8, tz = blockIdx.z * 8;
    const int rbx = tx - 3, rby = ty - 3, rbz = tz - 3;
    const float s2 = 127.0f / 63.0f;
    const float k = 1.0f / 256.0f;
    for (int i = tid; i < 2744; i += 256) {
        int xx = i % 14, yy = (i / 14) % 14, zz = i / 196;
        int gz = rbz + zz, gy = rby + yy, gx = rbx + xx;
        float v0 = 0.0f, v1 = 0.0f, v2 = 0.0f;
        if ((unsigned)gz < 64u && (unsigned)gy < 64u && (unsigned)gx < 64u) {
            float cz = gz * s2, cy = gy * s2, cx = gx * s2;
            // coords in [0,127]; clamp base so upper corner stays in-bounds
            int iz = min((int)cz, 126);
            int iy = min((int)cy, 126);
            int ix = min((int)cx, 126);
            float tzf = cz - (float)iz;
            float tyf = cy - (float)iy;
            float txf = cx - (float)ix;
            float wz[2] = {1.0f - tzf, tzf};
            float wy[2] = {1.0f - tyf, tyf};
            float wx[2] = {1.0f - txf, txf};
            int b = ((iz << 14) + (iy << 7) + ix) * 3;
#pragma unroll
            for (int dz = 0; dz < 2; ++dz)
#pragma unroll
                for (int dy = 0; dy < 2; ++dy)
#pragma unroll
                    for (int dx = 0; dx < 2; ++dx) {
                        float w = wz[dz] * wy[dy] * wx[dx];
                        int bb = b + dz * (3 << 14) + dy * (3 << 7) + dx * 3;
                        v0 += pf[bb] * w;
                        v1 += pf[bb + 1] * w;
                        v2 += pf[bb + 2] * w;
                    }
        }
        A[i] = v0 * k;
        A[i + 2744] = v1 * k;
        A[i + 2 * 2744] = v2 * k;
    }
    __syncthreads();
    step_lds<14>(A, B, tid);  // s1: 12^3 in B
    __syncthreads();
    step_lds<12>(B, A, tid);  // s2: 10^3 into A-mem
    __syncthreads();
    step_to_global(A, gout, tx, ty, tz, tid);  // s3 -> 8^3 global (interleaved)
}

// ------- F3: steps 4-6 (stage 14^3 from interleaved global) ----------------
__global__ __launch_bounds__(256) void f3_kernel(
    const float* __restrict__ gin, float* __restrict__ gout) {
    __shared__ float A[3 * 2744];
    __shared__ float B[3 * 1728];
    const int tid = threadIdx.x;
    const int tx = blockIdx.x * 8, ty = blockIdx.y * 8, tz = blockIdx.z * 8;
    const int rbx = tx - 3, rby = ty - 3, rbz = tz - 3;
    for (int i = tid; i < 2744; i += 256) {
        int xx = i % 14, yy = (i / 14) % 14, zz = i / 196;
        int gz = rbz + zz, gy = rby + yy, gx = rbx + xx;
        float v0 = 0.0f, v1 = 0.0f, v2 = 0.0f;
        if ((unsigned)gz < 64u && (unsigned)gy < 64u && (unsigned)gx < 64u) {
            int n3 = ((gz << 12) + (gy << 6) + gx) * 3;
            v0 = gin[n3];
            v1 = gin[n3 + 1];
            v2 = gin[n3 + 2];
        }
        A[i] = v0;
        A[i + 2744] = v1;
        A[i + 2 * 2744] = v2;
    }
    __syncthreads();
    step_lds<14>(A, B, tid);  // s4
    __syncthreads();
    step_lds<12>(B, A, tid);  // s5
    __syncthreads();
    step_to_global(A, gout, tx, ty, tz, tid);  // s6
}

// ------- F4: step 7 + upsample(x2) -> flow + label warp -> moved -----------
__global__ __launch_bounds__(256) void f4_kernel(
    const float* __restrict__ gin, const float* __restrict__ label,
    float* __restrict__ moved, float* __restrict__ flow) {
    __shared__ float A[3 * 2197];  // 13^3
    __shared__ float B[3 * 1331];  // 11^3
    const int tid = threadIdx.x;
    const int ttx = blockIdx.x, tty = blockIdx.y, ttz = blockIdx.z;
    const int r0x = (1008 * ttx) / 127 - 1;
    const int r0y = (1008 * tty) / 127 - 1;
    const int r0z = (1008 * ttz) / 127 - 1;
    const int rbx = r0x - 1, rby = r0y - 1, rbz = r0z - 1;
    for (int i = tid; i < 2197; i += 256) {
        int xx = i % 13, yy = (i / 13) % 13, zz = i / 169;
        int gz = rbz + zz, gy = rby + yy, gx = rbx + xx;
        float v0 = 0.0f, v1 = 0.0f, v2 = 0.0f;
        if ((unsigned)gz < 64u && (unsigned)gy < 64u && (unsigned)gx < 64u) {
            int n3 = ((gz << 12) + (gy << 6) + gx) * 3;
            v0 = gin[n3];
            v1 = gin[n3 + 1];
            v2 = gin[n3 + 2];
        }
        A[i] = v0;
        A[i + 2197] = v1;
        A[i + 2 * 2197] = v2;
    }
    __syncthreads();
    step_lds<13>(A, B, tid);  // s7: 11^3 in B, frame base = r0
    __syncthreads();
    const float s3 = 63.0f / 127.0f;
    for (int i = tid; i < 4096; i += 256) {
        int lx = i & 15, ly = (i >> 4) & 15, lz = i >> 8;
        int gx = ttx * 16 + lx, gy = tty * 16 + ly, gz = ttz * 16 + lz;
        float f[3];
        lds_lerp3<11>(B, gz * s3 - (float)r0z, gy * s3 - (float)r0y,
                      gx * s3 - (float)r0x, f);
        float fz = 2.0f * f[0], fy = 2.0f * f[1], fx = 2.0f * f[2];
        int m = (gz << 14) + (gy << 7) + gx;
        flow[m] = fz;
        flow[m + V128] = fy;
        flow[m + 2 * V128] = fx;
        float mv[1];
        trisample<1>(label, 128, 128, 128, 0, gz + fz, gy + fy, gx + fx, mv);
        moved[m] = mv[0];
    }
}

extern "C" void kernel_launch(void* const* d_in, const int* in_sizes, int n_in,
                              void* d_out, int out_size, void* d_ws,
                              size_t ws_size, hipStream_t stream) {
    const float* features = (const float*)d_in[0];
    const float* label = (const float*)d_in[1];
    const float* weight = (const float*)d_in[2];
    const float* bias = (const float*)d_in[3];
    float* out = (float*)d_out;
    float* moved = out;        // 128^3 floats
    float* flow = out + V128;  // 3*128^3 floats; also pos_flow scratch
    float* fA = (float*)d_ws;  // 3*64^3 floats (g3, interleaved [vox][3])
    float* fB = fA + 3 * V64;  // 3*64^3 floats (g6, interleaved [vox][3])

    conv_kernel<<<dim3(2, 32, 16), 256, 0, stream>>>(features, weight, bias,
                                                     flow);
    f2_kernel<<<dim3(8, 8, 8), 256, 0, stream>>>(flow, fA);
    f3_kernel<<<dim3(8, 8, 8), 256, 0, stream>>>(fA, fB);
    f4_kernel<<<dim3(8, 8, 8), 256, 0, stream>>>(fB, label, moved, flow);
}

// Round 5
// 325.340 us; speedup vs baseline: 1.9533x; 1.0190x over previous
//
#include <hip/hip_runtime.h>

// Problem: VoxelMorph flow pipeline.
// features [16,128,128,128] f32, moving_label [1,128,128,128] f32,
// weight [3,16,3,3,3] f32, bias [3] f32.
// Output: moved [128^3] then flow [3*128^3], f32, concatenated flat.
//
// R9 = R8 + two counter-driven fixes:
//  (1) conv LDS column stride 10 -> 11 floats (odd): lane bank = 11*lx mod 32
//      is bijective mod 32 -> 2 lanes/bank (free) vs the stride-10 4-way
//      conflict that cost 9.4M SQ_LDS_BANK_CONFLICT and +14us in R8.
//      Pair loads are 4B-aligned ds_read2_b32 (f32x2u).
//  (2) f2/f3/f4 at 512 threads/block (grid unchanged): 16 waves/CU instead
//      of 8 -> 4 waves/SIMD to hide the ~300cyc dependent LDS chain
//      (flow load -> addr -> 12 corner loads). Phases measured latency-bound
//      (~6.5% VALUBusy, 25% occupancy).
// Intermediates stay interleaved [vox][3] (12B/corner loads).

#define V128 2097152      // 128^3
#define V64  262144       // 64^3

typedef __attribute__((ext_vector_type(2))) float f32x2;
typedef float f32x2u __attribute__((ext_vector_type(2), aligned(4)));

// ---------------- trilinear sampler (bounds-checked; label warp) -----------
template <int C>
__device__ __forceinline__ void trisample(const float* __restrict__ vol,
                                          int D, int H, int W, int cstride,
                                          float cz, float cy, float cx,
                                          float* out) {
    float fz = floorf(cz), fy = floorf(cy), fx = floorf(cx);
    int iz = (int)fz, iy = (int)fy, ix = (int)fx;
    float tz = cz - fz, ty = cy - fy, tx = cx - fx;
#pragma unroll
    for (int c = 0; c < C; ++c) out[c] = 0.0f;
#pragma unroll
    for (int dz = 0; dz < 2; ++dz) {
#pragma unroll
        for (int dy = 0; dy < 2; ++dy) {
#pragma unroll
            for (int dx = 0; dx < 2; ++dx) {
                int z = iz + dz, y = iy + dy, x = ix + dx;
                float w = (dz ? tz : 1.0f - tz) *
                          (dy ? ty : 1.0f - ty) *
                          (dx ? tx : 1.0f - tx);
                bool valid = (z >= 0) && (z < D) && (y >= 0) && (y < H) &&
                             (x >= 0) && (x < W);
                int zc = min(max(z, 0), D - 1);
                int yc = min(max(y, 0), H - 1);
                int xc = min(max(x, 0), W - 1);
                int base = (zc * H + yc) * W + xc;
                float wv = valid ? w : 0.0f;
#pragma unroll
                for (int c = 0; c < C; ++c)
                    out[c] += vol[c * cstride + base] * wv;
            }
        }
    }
}

// -------- LDS trilerp, 3 channels, no bounds checks (caller guarantees) ----
template <int SI>
__device__ __forceinline__ void lds_lerp3(const float* __restrict__ f,
                                          float pz, float py, float px,
                                          float* out) {
    constexpr int NI = SI * SI * SI;
    float fz = floorf(pz), fy = floorf(py), fx = floorf(px);
    int iz = (int)fz, iy = (int)fy, ix = (int)fx;
    float tz = pz - fz, ty = py - fy, tx = px - fx;
    int b = (iz * SI + iy) * SI + ix;
    float wz0 = 1.0f - tz, wy0 = 1.0f - ty, wx0 = 1.0f - tx;
#pragma unroll
    for (int c = 0; c < 3; ++c) {
        const float* fc = f + c * NI;
        float v00 = fc[b] * wx0 + fc[b + 1] * tx;
        float v01 = fc[b + SI] * wx0 + fc[b + SI + 1] * tx;
        float v10 = fc[b + SI * SI] * wx0 + fc[b + SI * SI + 1] * tx;
        float v11 = fc[b + SI * SI + SI] * wx0 + fc[b + SI * SI + SI + 1] * tx;
        out[c] = wz0 * (wy0 * v00 + ty * v01) + tz * (wy0 * v10 + ty * v11);
    }
}

// -------- one integration step LDS->LDS; NT = threads in block -------------
template <int SI, int NT>
__device__ __forceinline__ void step_lds(const float* __restrict__ in,
                                         float* __restrict__ out, int tid) {
    constexpr int SO = SI - 2;
    constexpr int NI = SI * SI * SI;
    constexpr int NO = SO * SO * SO;
    for (int i = tid; i < NO; i += NT) {
        int xx = i % SO, yy = (i / SO) % SO, zz = i / (SO * SO);
        int la = ((zz + 1) * SI + (yy + 1)) * SI + (xx + 1);
        float fz = in[la], fy = in[la + NI], fx = in[la + 2 * NI];
        float sm[3];
        lds_lerp3<SI>(in, (zz + 1) + fz, (yy + 1) + fy, (xx + 1) + fx, sm);
        out[i] = fz + sm[0];
        out[i + NO] = fy + sm[1];
        out[i + 2 * NO] = fx + sm[2];
    }
}

// -------- last fused step: 10^3 region -> global 8^3, interleaved [vox][3] --
template <int NT>
__device__ __forceinline__ void step_to_global(const float* __restrict__ in,
                                               float* __restrict__ gout,
                                               int tx, int ty, int tz,
                                               int tid) {
    constexpr int SI = 10;
    constexpr int NI = SI * SI * SI;
    for (int i = tid; i < 512; i += NT) {
        int xx = i & 7, yy = (i >> 3) & 7, zz = i >> 6;
        int la = ((zz + 1) * SI + (yy + 1)) * SI + (xx + 1);
        float fz = in[la], fy = in[la + NI], fx = in[la + 2 * NI];
        float sm[3];
        lds_lerp3<SI>(in, (zz + 1) + fz, (yy + 1) + fy, (xx + 1) + fx, sm);
        int n3 = ((((tz + zz) << 12) + ((ty + yy) << 6) + (tx + xx))) * 3;
        gout[n3] = fz + sm[0];
        gout[n3 + 1] = fy + sm[1];
        gout[n3 + 2] = fx + sm[2];
    }
}

// ---------------- K1: conv3d 16->3, 3x3x3, pad 1 ---------------------------
// Staged tile: z-innermost with COLUMN STRIDE 11 (10 z-floats + 1 pad).
// Lane bank = 11*lx mod 32 -> bijective mod 32 -> conflict-free reads.
// s enumerates (zz = s%10, xx = (s/10)%66, yy = s/660); LDS addr =
// (s/10)*11 + s%10. Accumulation: f32x2 z-pairs via v_pk_fma_f32.
__global__ __launch_bounds__(256) void conv_kernel(
    const float* __restrict__ feat, const float* __restrict__ weight,
    const float* __restrict__ bias, float* __restrict__ pf) {
    __shared__ float smem[2][4356];  // 66*6 columns * 11
    const int tid = threadIdx.x;
    const int x0 = blockIdx.x * 64, y0 = blockIdx.y * 4, z0 = blockIdx.z * 8;
    const int lx = tid & 63, ly = tid >> 6;

    int goff[16];
    int laddr[16];
    unsigned vmask = 0;
#pragma unroll
    for (int k = 0; k < 16; ++k) {
        int s = tid + 256 * k;
        int col = s / 10;
        int zz = s - col * 10;
        int xx = col % 66;
        int yy = col / 66;
        laddr[k] = col * 11 + zz;
        bool intile = (k < 15) || (tid < 120);
        int gx = x0 + xx - 1, gy = y0 + yy - 1, gz = z0 + zz - 1;
        bool ok = intile && ((unsigned)gx < 128u) && ((unsigned)gy < 128u) &&
                  ((unsigned)gz < 128u);
        goff[k] = (gz << 14) + (gy << 7) + gx;
        if (ok) vmask |= (1u << k);
    }

    f32x2 acc[3][4];
#pragma unroll
    for (int o = 0; o < 3; ++o)
#pragma unroll
        for (int zp = 0; zp < 4; ++zp) acc[o][zp] = (f32x2)(0.0f);

    {
        float vals[16];
#pragma unroll
        for (int k = 0; k < 16; ++k) {
            vals[k] = 0.0f;
            if (vmask & (1u << k)) vals[k] = feat[goff[k]];
        }
#pragma unroll
        for (int k = 0; k < 16; ++k)
            if (k < 15 || tid < 120) smem[0][laddr[k]] = vals[k];
    }

    for (int c = 0; c < 16; ++c) {
        __syncthreads();
        if (c + 1 < 16) {
            const float* fc = feat + ((c + 1) << 21);
            float* buf = smem[(c + 1) & 1];
            float vals[16];
#pragma unroll
            for (int k = 0; k < 16; ++k) {
                vals[k] = 0.0f;
                if (vmask & (1u << k)) vals[k] = fc[goff[k]];
            }
#pragma unroll
            for (int k = 0; k < 16; ++k)
                if (k < 15 || tid < 120) buf[laddr[k]] = vals[k];
        }
        const float* buf = smem[c & 1];
        const float* wc = weight + c * 27;
#pragma unroll
        for (int dy = 0; dy < 3; ++dy) {
#pragma unroll
            for (int dx = 0; dx < 3; ++dx) {
                const float* p = buf + ((ly + dy) * 66 + lx + dx) * 11;
                f32x2 pv[5];
                f32x2 qv[4];
#pragma unroll
                for (int k2 = 0; k2 < 5; ++k2)
                    pv[k2] = *(const f32x2u*)(p + 2 * k2);
#pragma unroll
                for (int k2 = 0; k2 < 4; ++k2)
                    qv[k2] = *(const f32x2u*)(p + 2 * k2 + 1);
#pragma unroll
                for (int o = 0; o < 3; ++o) {
                    float w0 = wc[o * 432 + 0 + dy * 3 + dx];
                    float w1 = wc[o * 432 + 9 + dy * 3 + dx];
                    float w2 = wc[o * 432 + 18 + dy * 3 + dx];
#pragma unroll
                    for (int zp = 0; zp < 4; ++zp) {
                        acc[o][zp] += pv[zp] * (f32x2)(w0);
                        acc[o][zp] += qv[zp] * (f32x2)(w1);
                        acc[o][zp] += pv[zp + 1] * (f32x2)(w2);
                    }
                }
            }
        }
    }

    float b0 = bias[0], b1 = bias[1], b2 = bias[2];
#pragma unroll
    for (int zp = 0; zp < 4; ++zp) {
        int vox0 = ((z0 + 2 * zp) << 14) + ((y0 + ly) << 7) + x0 + lx;
#pragma unroll
        for (int h = 0; h < 2; ++h) {
            int m3 = (vox0 + (h << 14)) * 3;
            pf[m3] = (h ? acc[0][zp].y : acc[0][zp].x) + b0;
            pf[m3 + 1] = (h ? acc[1][zp].y : acc[1][zp].x) + b1;
            pf[m3 + 2] = (h ? acc[2][zp].y : acc[2][zp].x) + b2;
        }
    }
}

// ------- F2: downsample(x1/256) on 14^3 halo region, then steps 1-3 --------
// 512 threads. pf interleaved [vox][3]; corner base clamped to <=126/dim
// (coord exactly 127.0 -> i=126,t=1.0 == reference's zero-weight corner).
__global__ __launch_bounds__(512) void f2_kernel(
    const float* __restrict__ pf, float* __restrict__ gout) {
    __shared__ float A[3 * 2744];  // 14^3
    __shared__ float B[3 * 1728];  // 12^3
    const int tid = threadIdx.x;
    const int tx = blockIdx.x * 8, ty = blockIdx.y * 8, tz = blockIdx.z * 8;
    const int rbx = tx - 3, rby = ty - 3, rbz = tz - 3;
    const float s2 = 127.0f / 63.0f;
    const float k = 1.0f / 256.0f;
    for (int i = tid; i < 2744; i += 512) {
        int xx = i % 14, yy = (i / 14) % 14, zz = i / 196;
        int gz = rbz + zz, gy = rby + yy, gx = rbx + xx;
        float v0 = 0.0f, v1 = 0.0f, v2 = 0.0f;
        if ((unsigned)gz < 64u && (unsigned)gy < 64u && (unsigned)gx < 64u) {
            float cz = gz * s2, cy = gy * s2, cx = gx * s2;
            int iz = min((int)cz, 126);
            int iy = min((int)cy, 126);
            int ix = min((int)cx, 126);
            float tzf = cz - (float)iz;
            float tyf = cy - (float)iy;
            float txf = cx - (float)ix;
            float wz[2] = {1.0f - tzf, tzf};
            float wy[2] = {1.0f - tyf, tyf};
            float wx[2] = {1.0f - txf, txf};
            int b = ((iz << 14) + (iy << 7) + ix) * 3;
#pragma unroll
            for (int dz = 0; dz < 2; ++dz)
#pragma unroll
                for (int dy = 0; dy < 2; ++dy)
#pragma unroll
                    for (int dx = 0; dx < 2; ++dx) {
                        float w = wz[dz] * wy[dy] * wx[dx];
                        int bb = b + dz * (3 << 14) + dy * (3 << 7) + dx * 3;
                        v0 += pf[bb] * w;
                        v1 += pf[bb + 1] * w;
                        v2 += pf[bb + 2] * w;
                    }
        }
        A[i] = v0 * k;
        A[i + 2744] = v1 * k;
        A[i + 2 * 2744] = v2 * k;
    }
    __syncthreads();
    step_lds<14, 512>(A, B, tid);  // s1: 12^3 in B
    __syncthreads();
    step_lds<12, 512>(B, A, tid);  // s2: 10^3 into A-mem
    __syncthreads();
    step_to_global<512>(A, gout, tx, ty, tz, tid);  // s3 -> 8^3 global
}

// ------- F3: steps 4-6 (stage 14^3 from interleaved global), 512 thr -------
__global__ __launch_bounds__(512) void f3_kernel(
    const float* __restrict__ gin, float* __restrict__ gout) {
    __shared__ float A[3 * 2744];
    __shared__ float B[3 * 1728];
    const int tid = threadIdx.x;
    const int tx = blockIdx.x * 8, ty = blockIdx.y * 8, tz = blockIdx.z * 8;
    const int rbx = tx - 3, rby = ty - 3, rbz = tz - 3;
    for (int i = tid; i < 2744; i += 512) {
        int xx = i % 14, yy = (i / 14) % 14, zz = i / 196;
        int gz = rbz + zz, gy = rby + yy, gx = rbx + xx;
        float v0 = 0.0f, v1 = 0.0f, v2 = 0.0f;
        if ((unsigned)gz < 64u && (unsigned)gy < 64u && (unsigned)gx < 64u) {
            int n3 = ((gz << 12) + (gy << 6) + gx) * 3;
            v0 = gin[n3];
            v1 = gin[n3 + 1];
            v2 = gin[n3 + 2];
        }
        A[i] = v0;
        A[i + 2744] = v1;
        A[i + 2 * 2744] = v2;
    }
    __syncthreads();
    step_lds<14, 512>(A, B, tid);  // s4
    __syncthreads();
    step_lds<12, 512>(B, A, tid);  // s5
    __syncthreads();
    step_to_global<512>(A, gout, tx, ty, tz, tid);  // s6
}

// ------- F4: step 7 + upsample(x2) -> flow + label warp -> moved, 512 thr --
__global__ __launch_bounds__(512) void f4_kernel(
    const float* __restrict__ gin, const float* __restrict__ label,
    float* __restrict__ moved, float* __restrict__ flow) {
    __shared__ float A[3 * 2197];  // 13^3
    __shared__ float B[3 * 1331];  // 11^3
    const int tid = threadIdx.x;
    const int ttx = blockIdx.x, tty = blockIdx.y, ttz = blockIdx.z;
    const int r0x = (1008 * ttx) / 127 - 1;
    const int r0y = (1008 * tty) / 127 - 1;
    const int r0z = (1008 * ttz) / 127 - 1;
    const int rbx = r0x - 1, rby = r0y - 1, rbz = r0z - 1;
    for (int i = tid; i < 2197; i += 512) {
        int xx = i % 13, yy = (i / 13) % 13, zz = i / 169;
        int gz = rbz + zz, gy = rby + yy, gx = rbx + xx;
        float v0 = 0.0f, v1 = 0.0f, v2 = 0.0f;
        if ((unsigned)gz < 64u && (unsigned)gy < 64u && (unsigned)gx < 64u) {
            int n3 = ((gz << 12) + (gy << 6) + gx) * 3;
            v0 = gin[n3];
            v1 = gin[n3 + 1];
            v2 = gin[n3 + 2];
        }
        A[i] = v0;
        A[i + 2197] = v1;
        A[i + 2 * 2197] = v2;
    }
    __syncthreads();
    step_lds<13, 512>(A, B, tid);  // s7: 11^3 in B, frame base = r0
    __syncthreads();
    const float s3 = 63.0f / 127.0f;
    for (int i = tid; i < 4096; i += 512) {
        int lx = i & 15, ly = (i >> 4) & 15, lz = i >> 8;
        int gx = ttx * 16 + lx, gy = tty * 16 + ly, gz = ttz * 16 + lz;
        float f[3];
        lds_lerp3<11>(B, gz * s3 - (float)r0z, gy * s3 - (float)r0y,
                      gx * s3 - (float)r0x, f);
        float fz = 2.0f * f[0], fy = 2.0f * f[1], fx = 2.0f * f[2];
        int m = (gz << 14) + (gy << 7) + gx;
        flow[m] = fz;
        flow[m + V128] = fy;
        flow[m + 2 * V128] = fx;
        float mv[1];
        trisample<1>(label, 128, 128, 128, 0, gz + fz, gy + fy, gx + fx, mv);
        moved[m] = mv[0];
    }
}

extern "C" void kernel_launch(void* const* d_in, const int* in_sizes, int n_in,
                              void* d_out, int out_size, void* d_ws,
                              size_t ws_size, hipStream_t stream) {
    const float* features = (const float*)d_in[0];
    const float* label = (const float*)d_in[1];
    const float* weight = (const float*)d_in[2];
    const float* bias = (const float*)d_in[3];
    float* out = (float*)d_out;
    float* moved = out;        // 128^3 floats
    float* flow = out + V128;  // 3*128^3 floats; also pos_flow scratch
    float* fA = (float*)d_ws;  // 3*64^3 floats (g3, interleaved [vox][3])
    float* fB = fA + 3 * V64;  // 3*64^3 floats (g6, interleaved [vox][3])

    conv_kernel<<<dim3(2, 32, 16), 256, 0, stream>>>(features, weight, bias,
                                                     flow);
    f2_kernel<<<dim3(8, 8, 8), 512, 0, stream>>>(flow, fA);
    f3_kernel<<<dim3(8, 8, 8), 512, 0, stream>>>(fA, fB);
    f4_kernel<<<dim3(8, 8, 8), 512, 0, stream>>>(fB, label, moved, flow);
}

// Round 6
// 292.470 us; speedup vs baseline: 2.1728x; 1.1124x over previous
//
#include <hip/hip_runtime.h>

// Problem: VoxelMorph flow pipeline.
// features [16,128,128,128] f32, moving_label [1,128,128,128] f32,
// weight [3,16,3,3,3] f32, bias [3] f32.
// Output: moved [128^3] then flow [3*128^3], f32, concatenated flat.
//
// R10. Counter-driven deltas vs R9 (325us):
//  (1) conv: R9's z-innermost GLOBAL enumeration broke coalescing (lane
//      stride 64KB -> ~10 segments/wave; VALUBusy fell to 38% while dur
//      rose). Decouple: global loads x-innermost (contiguous 66-float runs,
//      R0's pattern) + LDS scatter-write z-innermost stride-11 (bijective
//      mod 32 banks). Keeps packed f32x2 FMA + conflict-free reads.
//  (2) f2's staging re-read a 28^3 span of the 24MB pos_flow per 8^3-output
//      block (~5.4x halo amplification ~135MB L3 traffic). New ds_kernel
//      computes downsample+1/256-scale ONCE (64^3, coalesced), stored in
//      the 'moved' output region as scratch (3.1MB, L2-resident; moved is
//      rewritten by f4 last). f2 then == f3: one f23_kernel launched twice.
// Dispatches: conv, ds, f23(x2), f4.

#define V128 2097152      // 128^3
#define V64  262144       // 64^3

typedef __attribute__((ext_vector_type(2))) float f32x2;
typedef float f32x2u __attribute__((ext_vector_type(2), aligned(4)));

// ---------------- trilinear sampler (bounds-checked; label warp) -----------
template <int C>
__device__ __forceinline__ void trisample(const float* __restrict__ vol,
                                          int D, int H, int W, int cstride,
                                          float cz, float cy, float cx,
                                          float* out) {
    float fz = floorf(cz), fy = floorf(cy), fx = floorf(cx);
    int iz = (int)fz, iy = (int)fy, ix = (int)fx;
    float tz = cz - fz, ty = cy - fy, tx = cx - fx;
#pragma unroll
    for (int c = 0; c < C; ++c) out[c] = 0.0f;
#pragma unroll
    for (int dz = 0; dz < 2; ++dz) {
#pragma unroll
        for (int dy = 0; dy < 2; ++dy) {
#pragma unroll
            for (int dx = 0; dx < 2; ++dx) {
                int z = iz + dz, y = iy + dy, x = ix + dx;
                float w = (dz ? tz : 1.0f - tz) *
                          (dy ? ty : 1.0f - ty) *
                          (dx ? tx : 1.0f - tx);
                bool valid = (z >= 0) && (z < D) && (y >= 0) && (y < H) &&
                             (x >= 0) && (x < W);
                int zc = min(max(z, 0), D - 1);
                int yc = min(max(y, 0), H - 1);
                int xc = min(max(x, 0), W - 1);
                int base = (zc * H + yc) * W + xc;
                float wv = valid ? w : 0.0f;
#pragma unroll
                for (int c = 0; c < C; ++c)
                    out[c] += vol[c * cstride + base] * wv;
            }
        }
    }
}

// -------- LDS trilerp, 3 channels, no bounds checks (caller guarantees) ----
template <int SI>
__device__ __forceinline__ void lds_lerp3(const float* __restrict__ f,
                                          float pz, float py, float px,
                                          float* out) {
    constexpr int NI = SI * SI * SI;
    float fz = floorf(pz), fy = floorf(py), fx = floorf(px);
    int iz = (int)fz, iy = (int)fy, ix = (int)fx;
    float tz = pz - fz, ty = py - fy, tx = px - fx;
    int b = (iz * SI + iy) * SI + ix;
    float wz0 = 1.0f - tz, wy0 = 1.0f - ty, wx0 = 1.0f - tx;
#pragma unroll
    for (int c = 0; c < 3; ++c) {
        const float* fc = f + c * NI;
        float v00 = fc[b] * wx0 + fc[b + 1] * tx;
        float v01 = fc[b + SI] * wx0 + fc[b + SI + 1] * tx;
        float v10 = fc[b + SI * SI] * wx0 + fc[b + SI * SI + 1] * tx;
        float v11 = fc[b + SI * SI + SI] * wx0 + fc[b + SI * SI + SI + 1] * tx;
        out[c] = wz0 * (wy0 * v00 + ty * v01) + tz * (wy0 * v10 + ty * v11);
    }
}

// -------- one integration step LDS->LDS; NT = threads in block -------------
template <int SI, int NT>
__device__ __forceinline__ void step_lds(const float* __restrict__ in,
                                         float* __restrict__ out, int tid) {
    constexpr int SO = SI - 2;
    constexpr int NI = SI * SI * SI;
    constexpr int NO = SO * SO * SO;
    for (int i = tid; i < NO; i += NT) {
        int xx = i % SO, yy = (i / SO) % SO, zz = i / (SO * SO);
        int la = ((zz + 1) * SI + (yy + 1)) * SI + (xx + 1);
        float fz = in[la], fy = in[la + NI], fx = in[la + 2 * NI];
        float sm[3];
        lds_lerp3<SI>(in, (zz + 1) + fz, (yy + 1) + fy, (xx + 1) + fx, sm);
        out[i] = fz + sm[0];
        out[i + NO] = fy + sm[1];
        out[i + 2 * NO] = fx + sm[2];
    }
}

// -------- last fused step: 10^3 region -> global 8^3, interleaved [vox][3] --
template <int NT>
__device__ __forceinline__ void step_to_global(const float* __restrict__ in,
                                               float* __restrict__ gout,
                                               int tx, int ty, int tz,
                                               int tid) {
    constexpr int SI = 10;
    constexpr int NI = SI * SI * SI;
    for (int i = tid; i < 512; i += NT) {
        int xx = i & 7, yy = (i >> 3) & 7, zz = i >> 6;
        int la = ((zz + 1) * SI + (yy + 1)) * SI + (xx + 1);
        float fz = in[la], fy = in[la + NI], fx = in[la + 2 * NI];
        float sm[3];
        lds_lerp3<SI>(in, (zz + 1) + fz, (yy + 1) + fy, (xx + 1) + fx, sm);
        int n3 = ((((tz + zz) << 12) + ((ty + yy) << 6) + (tx + xx))) * 3;
        gout[n3] = fz + sm[0];
        gout[n3 + 1] = fy + sm[1];
        gout[n3 + 2] = fx + sm[2];
    }
}

// ---------------- K1: conv3d 16->3, 3x3x3, pad 1 ---------------------------
// Global staging enumerated x-INNERMOST (s = tid+256k: xx=s%66, yy=(s/66)%6,
// zz=s/396) -> contiguous 66-float runs per wave (coalesced).
// LDS layout z-INNERMOST, column stride 11: addr = (yy*66+xx)*11 + zz.
// Scatter-write stride 11 floats -> bank 11*lane mod 32 bijective -> free.
// Reads: aligned-enough f32x2 pair loads; packed v_pk_fma_f32 accumulation.
__global__ __launch_bounds__(256) void conv_kernel(
    const float* __restrict__ feat, const float* __restrict__ weight,
    const float* __restrict__ bias, float* __restrict__ pf) {
    __shared__ float smem[2][4356];  // 396 columns * 11
    const int tid = threadIdx.x;
    const int x0 = blockIdx.x * 64, y0 = blockIdx.y * 4, z0 = blockIdx.z * 8;
    const int lx = tid & 63, ly = tid >> 6;

    int goff[16];
    int laddr[16];
    unsigned vmask = 0;
#pragma unroll
    for (int k = 0; k < 16; ++k) {
        int s = tid + 256 * k;
        int xx = s % 66;
        int r = s / 66;
        int yy = r % 6;
        int zz = r / 6;
        laddr[k] = (yy * 66 + xx) * 11 + zz;
        bool intile = (k < 15) || (tid < 120);
        int gx = x0 + xx - 1, gy = y0 + yy - 1, gz = z0 + zz - 1;
        bool ok = intile && ((unsigned)gx < 128u) && ((unsigned)gy < 128u) &&
                  ((unsigned)gz < 128u);
        goff[k] = (gz << 14) + (gy << 7) + gx;
        if (ok) vmask |= (1u << k);
    }

    f32x2 acc[3][4];
#pragma unroll
    for (int o = 0; o < 3; ++o)
#pragma unroll
        for (int zp = 0; zp < 4; ++zp) acc[o][zp] = (f32x2)(0.0f);

    {
        float vals[16];
#pragma unroll
        for (int k = 0; k < 16; ++k) {
            vals[k] = 0.0f;
            if (vmask & (1u << k)) vals[k] = feat[goff[k]];
        }
#pragma unroll
        for (int k = 0; k < 16; ++k)
            if (k < 15 || tid < 120) smem[0][laddr[k]] = vals[k];
    }

    for (int c = 0; c < 16; ++c) {
        __syncthreads();
        if (c + 1 < 16) {
            const float* fc = feat + ((c + 1) << 21);
            float* buf = smem[(c + 1) & 1];
            float vals[16];
#pragma unroll
            for (int k = 0; k < 16; ++k) {
                vals[k] = 0.0f;
                if (vmask & (1u << k)) vals[k] = fc[goff[k]];
            }
#pragma unroll
            for (int k = 0; k < 16; ++k)
                if (k < 15 || tid < 120) buf[laddr[k]] = vals[k];
        }
        const float* buf = smem[c & 1];
        const float* wc = weight + c * 27;
#pragma unroll
        for (int dy = 0; dy < 3; ++dy) {
#pragma unroll
            for (int dx = 0; dx < 3; ++dx) {
                const float* p = buf + ((ly + dy) * 66 + lx + dx) * 11;
                f32x2 pv[5];
                f32x2 qv[4];
#pragma unroll
                for (int k2 = 0; k2 < 5; ++k2)
                    pv[k2] = *(const f32x2u*)(p + 2 * k2);
#pragma unroll
                for (int k2 = 0; k2 < 4; ++k2)
                    qv[k2] = *(const f32x2u*)(p + 2 * k2 + 1);
#pragma unroll
                for (int o = 0; o < 3; ++o) {
                    float w0 = wc[o * 432 + 0 + dy * 3 + dx];
                    float w1 = wc[o * 432 + 9 + dy * 3 + dx];
                    float w2 = wc[o * 432 + 18 + dy * 3 + dx];
#pragma unroll
                    for (int zp = 0; zp < 4; ++zp) {
                        acc[o][zp] += pv[zp] * (f32x2)(w0);
                        acc[o][zp] += qv[zp] * (f32x2)(w1);
                        acc[o][zp] += pv[zp + 1] * (f32x2)(w2);
                    }
                }
            }
        }
    }

    float b0 = bias[0], b1 = bias[1], b2 = bias[2];
#pragma unroll
    for (int zp = 0; zp < 4; ++zp) {
        int vox0 = ((z0 + 2 * zp) << 14) + ((y0 + ly) << 7) + x0 + lx;
#pragma unroll
        for (int h = 0; h < 2; ++h) {
            int m3 = (vox0 + (h << 14)) * 3;
            pf[m3] = (h ? acc[0][zp].y : acc[0][zp].x) + b0;
            pf[m3 + 1] = (h ? acc[1][zp].y : acc[1][zp].x) + b1;
            pf[m3 + 2] = (h ? acc[2][zp].y : acc[2][zp].x) + b2;
        }
    }
}

// ------- K2: downsample(127/63) + 1/256 scale, 128^3 -> 64^3 ---------------
// pf interleaved [vox][3]; out dsf interleaved [vox][3] (3.1MB, L2-resident
// for the f23 consumers). Corner base clamped to <=126/dim (coord exactly
// 127.0 -> i=126,t=1.0 == reference's zero-weight masked corner, exact).
__global__ __launch_bounds__(256) void ds_kernel(const float* __restrict__ pf,
                                                 float* __restrict__ dsf) {
    int i = blockIdx.x * 256 + threadIdx.x;  // 64^3 samples
    int gx = i & 63, gy = (i >> 6) & 63, gz = i >> 12;
    const float s2 = 127.0f / 63.0f;
    const float k = 1.0f / 256.0f;
    float cz = gz * s2, cy = gy * s2, cx = gx * s2;
    int iz = min((int)cz, 126);
    int iy = min((int)cy, 126);
    int ix = min((int)cx, 126);
    float tzf = cz - (float)iz;
    float tyf = cy - (float)iy;
    float txf = cx - (float)ix;
    float wz[2] = {1.0f - tzf, tzf};
    float wy[2] = {1.0f - tyf, tyf};
    float wx[2] = {1.0f - txf, txf};
    int b = ((iz << 14) + (iy << 7) + ix) * 3;
    float v0 = 0.0f, v1 = 0.0f, v2 = 0.0f;
#pragma unroll
    for (int dz = 0; dz < 2; ++dz)
#pragma unroll
        for (int dy = 0; dy < 2; ++dy)
#pragma unroll
            for (int dx = 0; dx < 2; ++dx) {
                float w = wz[dz] * wy[dy] * wx[dx];
                int bb = b + dz * (3 << 14) + dy * (3 << 7) + dx * 3;
                v0 += pf[bb] * w;
                v1 += pf[bb + 1] * w;
                v2 += pf[bb + 2] * w;
            }
    int o3 = i * 3;
    dsf[o3] = v0 * k;
    dsf[o3 + 1] = v1 * k;
    dsf[o3 + 2] = v2 * k;
}

// ------- F23: three integration steps (stage 14^3 from interleaved 64^3) ---
// Used twice: (dsf -> fA) = steps 1-3, (fA -> fB) = steps 4-6.
__global__ __launch_bounds__(512) void f23_kernel(
    const float* __restrict__ gin, float* __restrict__ gout) {
    __shared__ float A[3 * 2744];
    __shared__ float B[3 * 1728];
    const int tid = threadIdx.x;
    const int tx = blockIdx.x * 8, ty = blockIdx.y * 8, tz = blockIdx.z * 8;
    const int rbx = tx - 3, rby = ty - 3, rbz = tz - 3;
    for (int i = tid; i < 2744; i += 512) {
        int xx = i % 14, yy = (i / 14) % 14, zz = i / 196;
        int gz = rbz + zz, gy = rby + yy, gx = rbx + xx;
        float v0 = 0.0f, v1 = 0.0f, v2 = 0.0f;
        if ((unsigned)gz < 64u && (unsigned)gy < 64u && (unsigned)gx < 64u) {
            int n3 = ((gz << 12) + (gy << 6) + gx) * 3;
            v0 = gin[n3];
            v1 = gin[n3 + 1];
            v2 = gin[n3 + 2];
        }
        A[i] = v0;
        A[i + 2744] = v1;
        A[i + 2 * 2744] = v2;
    }
    __syncthreads();
    step_lds<14, 512>(A, B, tid);
    __syncthreads();
    step_lds<12, 512>(B, A, tid);
    __syncthreads();
    step_to_global<512>(A, gout, tx, ty, tz, tid);
}

// ------- F4: step 7 + upsample(x2) -> flow + label warp -> moved, 512 thr --
__global__ __launch_bounds__(512) void f4_kernel(
    const float* __restrict__ gin, const float* __restrict__ label,
    float* __restrict__ moved, float* __restrict__ flow) {
    __shared__ float A[3 * 2197];  // 13^3
    __shared__ float B[3 * 1331];  // 11^3
    const int tid = threadIdx.x;
    const int ttx = blockIdx.x, tty = blockIdx.y, ttz = blockIdx.z;
    const int r0x = (1008 * ttx) / 127 - 1;
    const int r0y = (1008 * tty) / 127 - 1;
    const int r0z = (1008 * ttz) / 127 - 1;
    const int rbx = r0x - 1, rby = r0y - 1, rbz = r0z - 1;
    for (int i = tid; i < 2197; i += 512) {
        int xx = i % 13, yy = (i / 13) % 13, zz = i / 169;
        int gz = rbz + zz, gy = rby + yy, gx = rbx + xx;
        float v0 = 0.0f, v1 = 0.0f, v2 = 0.0f;
        if ((unsigned)gz < 64u && (unsigned)gy < 64u && (unsigned)gx < 64u) {
            int n3 = ((gz << 12) + (gy << 6) + gx) * 3;
            v0 = gin[n3];
            v1 = gin[n3 + 1];
            v2 = gin[n3 + 2];
        }
        A[i] = v0;
        A[i + 2197] = v1;
        A[i + 2 * 2197] = v2;
    }
    __syncthreads();
    step_lds<13, 512>(A, B, tid);  // s7: 11^3 in B, frame base = r0
    __syncthreads();
    const float s3 = 63.0f / 127.0f;
    for (int i = tid; i < 4096; i += 512) {
        int lx = i & 15, ly = (i >> 4) & 15, lz = i >> 8;
        int gx = ttx * 16 + lx, gy = tty * 16 + ly, gz = ttz * 16 + lz;
        float f[3];
        lds_lerp3<11>(B, gz * s3 - (float)r0z, gy * s3 - (float)r0y,
                      gx * s3 - (float)r0x, f);
        float fz = 2.0f * f[0], fy = 2.0f * f[1], fx = 2.0f * f[2];
        int m = (gz << 14) + (gy << 7) + gx;
        flow[m] = fz;
        flow[m + V128] = fy;
        flow[m + 2 * V128] = fx;
        float mv[1];
        trisample<1>(label, 128, 128, 128, 0, gz + fz, gy + fy, gx + fx, mv);
        moved[m] = mv[0];
    }
}

extern "C" void kernel_launch(void* const* d_in, const int* in_sizes, int n_in,
                              void* d_out, int out_size, void* d_ws,
                              size_t ws_size, hipStream_t stream) {
    const float* features = (const float*)d_in[0];
    const float* label = (const float*)d_in[1];
    const float* weight = (const float*)d_in[2];
    const float* bias = (const float*)d_in[3];
    float* out = (float*)d_out;
    float* moved = out;        // 128^3 floats (final); dsf scratch before f4
    float* flow = out + V128;  // 3*128^3 floats; pf scratch (interleaved)
    float* dsf = moved;        // 3*64^3 = 786K floats < 2M: fits in moved
    float* fA = (float*)d_ws;  // 3*64^3 floats (g3, interleaved [vox][3])
    float* fB = fA + 3 * V64;  // 3*64^3 floats (g6, interleaved [vox][3])

    conv_kernel<<<dim3(2, 32, 16), 256, 0, stream>>>(features, weight, bias,
                                                     flow);
    ds_kernel<<<dim3(1024), 256, 0, stream>>>(flow, dsf);
    f23_kernel<<<dim3(8, 8, 8), 512, 0, stream>>>(dsf, fA);  // steps 1-3
    f23_kernel<<<dim3(8, 8, 8), 512, 0, stream>>>(fA, fB);   // steps 4-6
    f4_kernel<<<dim3(8, 8, 8), 512, 0, stream>>>(fB, label, moved, flow);
}